// Round 1
// 262.489 us; speedup vs baseline: 1.0332x; 1.0332x over previous
//
#include <hip/hip_runtime.h>
#include <hip/hip_bf16.h>

// FlowNetC correlation via bf16 MFMA band-GEMM.
// out[b, (dy+4)*9+(dx+4), y, x] = (1/256) * sum_c in1[b,c,y,x] * in2[b,c,y+dy,x+dx]
// B=8, C=256, H=96, W=128, MD=4.
//
// v3: split the old 1024-thread block (8 rows x 32 px) into TWO 512-thread
// blocks (8 rows x 16 px). Rationale (rocprof): kernel sits at the 128-reg
// occupancy tier (56 VGPR + 72 acc AGPR) -> 16 waves/CU max -> the old
// 16-wave block meant exactly ONE resident block/CU: barriers drained the
// whole CU and grid=384 left half the CUs idle in round 2 (Occupancy 34%).
// Now 2 independent 8-wave barrier groups overlap stage/compute per CU,
// and the tail round runs 1 block on EVERY CU.
//
// Block = (b, 8-row y-tile, 16-px x-eighth), 512 threads (8 waves).
// LDS per 32-ch chunk: in1 8x16 slots, in2 16x32 slots (+-8 px, +-4 row halo),
// 64 B per pixel slot -> 40 KB. 2 blocks/CU = 80 KB.
// Wave = (ut, yrh): 2 u-tiles x 4 y-row-pairs.

#define B_ 8
#define C_ 256
#define H_ 96
#define W_ 128
#define HW_ 12288
#define CHW_ 3145728

#define IN1_OFF 0            // 8*16 = 128 slots
#define IN2_OFF 8192         // in2: 16*32 = 512 slots
#define IN2_ROWB (32 * 64)   // bytes per in2 LDS row

typedef __attribute__((ext_vector_type(8))) short short8;
typedef __attribute__((ext_vector_type(4))) float f32x4;

// bank swizzle on the 16B channel-group within a 64B pixel slot
__device__ __forceinline__ int swz16(int g, int slot) {
    return (g ^ (slot & 3) ^ ((slot >> 2) & 3)) * 16;
}

// load 8 channels x 4 px (float4, stride HW) -> bf16 -> four b128 LDS writes
__device__ __forceinline__ void stage16(const float* __restrict__ sp, char* __restrict__ base,
                                        int slot, int g) {
    f32x4 v[8];
    #pragma unroll
    for (int j = 0; j < 8; ++j) v[j] = *(const f32x4*)(sp + (size_t)j * HW_);
    #pragma unroll
    for (int p = 0; p < 4; ++p) {
        union { __hip_bfloat162 h2[4]; short8 s8; } u;
        #pragma unroll
        for (int jj = 0; jj < 4; ++jj)
            u.h2[jj] = __float22bfloat162_rn(float2{v[2 * jj][p], v[2 * jj + 1][p]});
        *(short8*)(base + (slot + p) * 64 + swz16(g, slot + p)) = u.s8;
    }
}

__global__ __launch_bounds__(512, 4) void corr_mfma3(
    const float* __restrict__ in1,
    const float* __restrict__ in2,
    float* __restrict__ out)
{
    __shared__ __align__(16) char lds[40960];

    const int tid = threadIdx.x;

    // XCD swizzle: blk%8 -> XCD; each XCD owns one batch image, y-major walk.
    const int blk  = blockIdx.x;
    const int b    = blk & 7;
    const int rest = blk >> 3;        // 0..95
    const int yt   = rest >> 3;       // 0..11 (8-row tiles)
    const int xh   = rest & 7;        // 0..7  (16-px eighths)

    // zero LDS once: halo/OOB slots stay zero for every chunk
    #pragma unroll
    for (int k = 0; k < 5; ++k)
        *(f32x4*)(lds + tid * 16 + k * 8192) = f32x4{0.f, 0.f, 0.f, 0.f};

    // ---- compute ids ----
    const int lane = tid & 63;
    const int wv   = tid >> 6;              // 0..7
    const int ut   = wv & 1;
    const int yrh  = wv >> 1;               // 0..3 -> y rows 2*yrh, 2*yrh+1
    const int ln   = lane & 15;
    const int qd   = lane >> 4;

    const int offA0 = IN1_OFF + ((2 * yrh) * 16 + ln) * 64 + swz16(qd, ln);
    const int pB    = 16 * ut + ln;                          // in2 slot px (0..31)
    const int offB  = IN2_OFF + ((2 * yrh) * 32 + pB) * 64 + swz16(qd, pB);

    const float* in1b = in1 + (size_t)b * CHW_;
    const float* in2b = in2 + (size_t)b * CHW_;

    // ---- chunk-invariant staging assignments ----
    // in2: 512 items (16 rows x 8 px-quads x 4 ch-groups), one per thread
    const int pp2 = tid & 7;
    const int g2  = (tid >> 3) & 3;
    const int r2  = tid >> 5;               // 0..15
    const int px2 = 4 * pp2;
    const int gx2 = xh * 16 - 8 + px2;      // aligned to 4 -> no straddle at W edges
    const int ry2 = yt * 8 - 4 + r2;
    const bool valid2 = (gx2 >= 0) && (gx2 <= 124) && (ry2 >= 0) && (ry2 < H_);
    const int slot2 = r2 * 32 + px2;

    // in1: 128 items (8 rows x 4 px-quads x 4 ch-groups), threads 0..127
    const int pp1 = tid & 3;
    const int g1  = (tid >> 2) & 3;
    const int r1  = tid >> 4;               // 0..7 (for tid<128)
    const int px1 = 4 * pp1;
    const int gx1 = xh * 16 + px1;
    const int y1  = yt * 8 + r1;
    const int slot1 = r1 * 16 + px1;

    f32x4 acc0[9], acc1[9];
    #pragma unroll
    for (int s = 0; s < 9; ++s) { acc0[s] = f32x4{0.f,0.f,0.f,0.f}; acc1[s] = f32x4{0.f,0.f,0.f,0.f}; }

    __syncthreads();   // zero-fill visible

    for (int kc = 0; kc < 8; ++kc) {
        const size_t choff = (size_t)(kc * 32) * HW_;
        // ---------------- stage ----------------
        if (valid2)
            stage16(in2b + choff + (size_t)(8 * g2) * HW_ + ry2 * W_ + gx2,
                    lds + IN2_OFF, slot2, g2);
        if (tid < 128)
            stage16(in1b + choff + (size_t)(8 * g1) * HW_ + y1 * W_ + gx1,
                    lds + IN1_OFF, slot1, g1);
        __syncthreads();
        // ---------------- MFMA: 2 A-frags, rolling B-window ----------------
        short8 a0  = *(const short8*)(lds + offA0);
        short8 a1  = *(const short8*)(lds + offA0 + 16 * 64);
        short8 blo = *(const short8*)(lds + offB);
        #pragma unroll
        for (int s = 0; s < 9; ++s) {
            short8 bhi = *(const short8*)(lds + offB + (s + 1) * IN2_ROWB);
            acc0[s] = __builtin_amdgcn_mfma_f32_16x16x32_bf16(a0, blo, acc0[s], 0, 0, 0);
            acc1[s] = __builtin_amdgcn_mfma_f32_16x16x32_bf16(a1, bhi, acc1[s], 0, 0, 0);
            blo = bhi;
        }
        __syncthreads();
    }

    // ---------------- epilogue: band extraction ----------------
    // D: col n = ln -> u = xh*16 - 8 + 16*ut + ln; row m = qd*4+r -> x = x0+m
    const float scale = 1.0f / 256.0f;
    const int x0 = xh * 16;
    const int ybase = yt * 8 + 2 * yrh;
    #pragma unroll
    for (int s = 0; s < 9; ++s) {
        #pragma unroll
        for (int yr = 0; yr < 2; ++yr) {
            const f32x4 a = yr ? acc1[s] : acc0[s];
            const int y = ybase + yr;
            #pragma unroll
            for (int r = 0; r < 4; ++r) {
                const int m  = qd * 4 + r;
                const int dx = ln - m - 8 + 16 * ut;
                if (dx >= -4 && dx <= 4) {
                    out[(((size_t)b * 81 + (size_t)(s * 9 + dx + 4)) * H_ + y) * W_ + (x0 + m)]
                        = a[r] * scale;
                }
            }
        }
    }
}

extern "C" void kernel_launch(void* const* d_in, const int* in_sizes, int n_in,
                              void* d_out, int out_size, void* d_ws, size_t ws_size,
                              hipStream_t stream) {
    const float* in1 = (const float*)d_in[0];
    const float* in2 = (const float*)d_in[1];
    float* out = (float*)d_out;

    // 8 b x 12 y-tiles x 8 x-eighths = 768 blocks of 512 threads
    corr_mfma3<<<768, 512, 0, stream>>>(in1, in2, out);
}

// Round 2
// 251.524 us; speedup vs baseline: 1.0783x; 1.0436x over previous
//
#include <hip/hip_runtime.h>
#include <hip/hip_bf16.h>

// FlowNetC correlation via bf16 MFMA band-GEMM.
// out[b, (dy+4)*9+(dx+4), y, x] = (1/256) * sum_c in1[b,c,y,x] * in2[b,c,y+dy,x+dx]
// B=8, C=256, H=96, W=128, MD=4.
//
// v4: software-pipelined chunks (T14 async-STAGE split + LDS double-buffer).
// rocprof v3: MfmaUtil 4.5%, VALUBusy 8.5%, HBM 15%, Occ 33% -> latency-bound:
// each chunk serialized {global load wait -> convert -> ds_write -> barrier ->
// tiny compute}. Now chunk k+1's global loads are issued BEFORE chunk k's
// compute and consumed after, with raw s_barrier + explicit lgkmcnt(0) only
// (no __syncthreads vmcnt drain). One barrier per chunk (double-buffer makes
// the second redundant). Staging rebalanced: every thread holds exactly
// 10 float4 in flight (in2: 8, in1: 2), no straggler waves.
//
// Block = (b, 8-row y-tile, 16-px x-eighth), 512 threads (8 waves).
// LDS: 2 buffers x 40 KB (in1 8x16 slots, in2 16x32 slots, 64 B/slot).
// Wave = (ut, yrh): 2 u-tiles x 4 y-row-pairs.

#define B_ 8
#define C_ 256
#define H_ 96
#define W_ 128
#define HW_ 12288
#define CHW_ 3145728

#define BUFSZ 40960
#define IN1_OFF 0            // in1: 8*16 = 128 slots
#define IN2_OFF 8192         // in2: 16*32 = 512 slots
#define IN2_ROWB (32 * 64)   // bytes per in2 LDS row

typedef __attribute__((ext_vector_type(8))) short short8;
typedef __attribute__((ext_vector_type(4))) float f32x4;

// bank swizzle on the 16B channel-group within a 64B pixel slot
__device__ __forceinline__ int swz16(int g, int slot) {
    return (g ^ (slot & 3) ^ ((slot >> 2) & 3)) * 16;
}

__global__ __launch_bounds__(512, 2) void corr_mfma4(
    const float* __restrict__ in1,
    const float* __restrict__ in2,
    float* __restrict__ out)
{
    __shared__ __align__(16) char lds[2 * BUFSZ];

    const int tid = threadIdx.x;

    // XCD swizzle: blk%8 -> XCD; each XCD owns one batch image, y-major walk.
    const int blk  = blockIdx.x;
    const int b    = blk & 7;
    const int rest = blk >> 3;        // 0..95
    const int yt   = rest >> 3;       // 0..11 (8-row tiles)
    const int xh   = rest & 7;        // 0..7  (16-px eighths)

    // zero both buffers once: halo/OOB slots stay zero for every chunk
    #pragma unroll
    for (int k = 0; k < 10; ++k)
        *(f32x4*)(lds + tid * 16 + k * 8192) = f32x4{0.f, 0.f, 0.f, 0.f};

    // ---- compute ids ----
    const int lane = tid & 63;
    const int wv   = tid >> 6;              // 0..7
    const int ut   = wv & 1;
    const int yrh  = wv >> 1;               // 0..3 -> y rows 2*yrh, 2*yrh+1
    const int ln   = lane & 15;
    const int qd   = lane >> 4;

    const int offA0 = IN1_OFF + ((2 * yrh) * 16 + ln) * 64 + swz16(qd, ln);
    const int pB    = 16 * ut + ln;                          // in2 slot px (0..31)
    const int offB  = IN2_OFF + ((2 * yrh) * 32 + pB) * 64 + swz16(qd, pB);

    const float* in1b = in1 + (size_t)b * CHW_;
    const float* in2b = in2 + (size_t)b * CHW_;

    // ---- chunk-invariant staging assignments ----
    // in2: 512 units (16 rows x 8 px-quads x 4 ch-groups), 8 float4 each
    const int pp2 = tid & 7;
    const int g2  = (tid >> 3) & 3;
    const int r2i = tid >> 5;               // 0..15
    const int px2 = 4 * pp2;
    const int gx2 = xh * 16 - 8 + px2;      // aligned to 4 -> no straddle at W edges
    const int ry2 = yt * 8 - 4 + r2i;
    const bool valid2 = (gx2 >= 0) && (gx2 <= 124) && (ry2 >= 0) && (ry2 < H_);
    const int slot2 = r2i * 32 + px2;
    const float* sp2base = in2b + (size_t)(8 * g2) * HW_ + ry2 * W_ + gx2;

    // in1: 512 units (8 rows x 4 px-quads x 4 ch-groups x 4 ch-pairs), 2 float4 each
    const int pq1 = tid & 3;
    const int jj1 = (tid >> 2) & 3;
    const int g1  = (tid >> 4) & 3;
    const int r1i = tid >> 6;               // 0..7
    const int px1 = 4 * pq1;
    const int gx1 = xh * 16 + px1;
    const int y1  = yt * 8 + r1i;
    const int slot1 = r1i * 16 + px1;
    const float* sp1base = in1b + (size_t)(8 * g1 + 2 * jj1) * HW_ + y1 * W_ + gx1;

    f32x4 r2[8], r1v[2];

    auto issue = [&](int kc) {
        const size_t ch = (size_t)kc * 32 * HW_;
        if (valid2) {
            #pragma unroll
            for (int j = 0; j < 8; ++j)
                r2[j] = *(const f32x4*)(sp2base + ch + (size_t)j * HW_);
        }
        r1v[0] = *(const f32x4*)(sp1base + ch);
        r1v[1] = *(const f32x4*)(sp1base + ch + HW_);
    };

    auto store = [&](char* __restrict__ buf) {
        if (valid2) {
            #pragma unroll
            for (int p = 0; p < 4; ++p) {
                union { __hip_bfloat162 h2[4]; short8 s8; } u;
                #pragma unroll
                for (int jj = 0; jj < 4; ++jj)
                    u.h2[jj] = __float22bfloat162_rn(float2{r2[2 * jj][p], r2[2 * jj + 1][p]});
                *(short8*)(buf + IN2_OFF + (slot2 + p) * 64 + swz16(g2, slot2 + p)) = u.s8;
            }
        }
        #pragma unroll
        for (int p = 0; p < 4; ++p) {
            __hip_bfloat162 h = __float22bfloat162_rn(float2{r1v[0][p], r1v[1][p]});
            *(__hip_bfloat162*)(buf + IN1_OFF + (slot1 + p) * 64 + swz16(g1, slot1 + p) + 4 * jj1) = h;
        }
    };

    f32x4 acc0[9], acc1[9];
    #pragma unroll
    for (int s = 0; s < 9; ++s) { acc0[s] = f32x4{0.f,0.f,0.f,0.f}; acc1[s] = f32x4{0.f,0.f,0.f,0.f}; }

    __syncthreads();   // zero-fill visible (no loads in flight yet)

    issue(0);

    for (int kc = 0; kc < 8; ++kc) {
        char* buf = lds + (kc & 1) * BUFSZ;
        store(buf);                 // waits (vmcnt) only on chunk-kc regs
        if (kc < 7) issue(kc + 1);  // fire next chunk's loads; in flight across barrier
        asm volatile("s_waitcnt lgkmcnt(0)" ::: "memory");   // ds_writes retired
        __builtin_amdgcn_s_barrier();                        // raw: no vmcnt drain
        asm volatile("" ::: "memory");
        // ---------------- MFMA: 2 A-frags, rolling B-window ----------------
        short8 a0  = *(const short8*)(buf + offA0);
        short8 a1  = *(const short8*)(buf + offA0 + 16 * 64);
        short8 blo = *(const short8*)(buf + offB);
        #pragma unroll
        for (int s = 0; s < 9; ++s) {
            short8 bhi = *(const short8*)(buf + offB + (s + 1) * IN2_ROWB);
            acc0[s] = __builtin_amdgcn_mfma_f32_16x16x32_bf16(a0, blo, acc0[s], 0, 0, 0);
            acc1[s] = __builtin_amdgcn_mfma_f32_16x16x32_bf16(a1, bhi, acc1[s], 0, 0, 0);
            blo = bhi;
        }
        // no second barrier: next iter writes the OTHER buffer; the lgkmcnt(0)
        // before the next barrier also drains this iter's ds_reads.
    }

    // ---------------- epilogue: band extraction ----------------
    // D: col n = ln -> u = xh*16 - 8 + 16*ut + ln; row m = qd*4+r -> x = x0+m
    const float scale = 1.0f / 256.0f;
    const int x0 = xh * 16;
    const int ybase = yt * 8 + 2 * yrh;
    #pragma unroll
    for (int s = 0; s < 9; ++s) {
        #pragma unroll
        for (int yr = 0; yr < 2; ++yr) {
            const f32x4 a = yr ? acc1[s] : acc0[s];
            const int y = ybase + yr;
            #pragma unroll
            for (int r = 0; r < 4; ++r) {
                const int m  = qd * 4 + r;
                const int dx = ln - m - 8 + 16 * ut;
                if (dx >= -4 && dx <= 4) {
                    out[(((size_t)b * 81 + (size_t)(s * 9 + dx + 4)) * H_ + y) * W_ + (x0 + m)]
                        = a[r] * scale;
                }
            }
        }
    }
}

extern "C" void kernel_launch(void* const* d_in, const int* in_sizes, int n_in,
                              void* d_out, int out_size, void* d_ws, size_t ws_size,
                              hipStream_t stream) {
    const float* in1 = (const float*)d_in[0];
    const float* in2 = (const float*)d_in[1];
    float* out = (float*)d_out;

    // 8 b x 12 y-tiles x 8 x-eighths = 768 blocks of 512 threads
    corr_mfma4<<<768, 512, 0, stream>>>(in1, in2, out);
}

// Round 4
// 247.456 us; speedup vs baseline: 1.0960x; 1.0164x over previous
//
#include <hip/hip_runtime.h>
#include <hip/hip_bf16.h>

// FlowNetC correlation via bf16 MFMA band-GEMM.
// out[b, (dy+4)*9+(dx+4), y, x] = (1/256) * sum_c in1[b,c,y,x] * in2[b,c,y+dy,x+dx]
// B=8, C=256, H=96, W=128, MD=4.
//
// v5 (resubmission — previous round's bench was an infra failure, kernel
// unchanged): coalesced epilogue via LDS transpose. rocprof v2-v4: every
// main-loop restructure moved only ~10%; the invariant cost was the
// band-extraction epilogue, whose per-instruction store pattern is ~36 lanes
// x 4 B at 49 KB stride (channel-major scatter) = ~8M single-dword L2 write
// transactions. Now: per dy-phase, waves scatter band values into a 4.6 KB
// LDS tile ep[y][dx][x] (cheap ds_writes), raw-barrier, then wave wv reads
// row y=wv contiguously and stores 4 x 64 B contiguous chunks per
// instruction. Main loop is byte-identical to v4 (software-pipelined, LDS
// double-buffer, raw s_barrier with loads in flight across it).
//
// Block = (b, 8-row y-tile, 16-px x-eighth), 512 threads (8 waves).
// LDS: 2 buffers x 40 KB (in1 8x16 slots, in2 16x32 slots, 64 B/slot).
// Wave = (ut, yrh): 2 u-tiles x 4 y-row-pairs.

#define B_ 8
#define C_ 256
#define H_ 96
#define W_ 128
#define HW_ 12288
#define CHW_ 3145728

#define BUFSZ 40960
#define IN1_OFF 0            // in1: 8*16 = 128 slots
#define IN2_OFF 8192         // in2: 16*32 = 512 slots
#define IN2_ROWB (32 * 64)   // bytes per in2 LDS row

typedef __attribute__((ext_vector_type(8))) short short8;
typedef __attribute__((ext_vector_type(4))) float f32x4;

// bank swizzle on the 16B channel-group within a 64B pixel slot
__device__ __forceinline__ int swz16(int g, int slot) {
    return (g ^ (slot & 3) ^ ((slot >> 2) & 3)) * 16;
}

__global__ __launch_bounds__(512, 2) void corr_mfma5(
    const float* __restrict__ in1,
    const float* __restrict__ in2,
    float* __restrict__ out)
{
    __shared__ __align__(16) char lds[2 * BUFSZ];

    const int tid = threadIdx.x;

    // XCD swizzle: blk%8 -> XCD; each XCD owns one batch image, y-major walk.
    const int blk  = blockIdx.x;
    const int b    = blk & 7;
    const int rest = blk >> 3;        // 0..95
    const int yt   = rest >> 3;       // 0..11 (8-row tiles)
    const int xh   = rest & 7;        // 0..7  (16-px eighths)

    // zero both buffers once: halo/OOB slots stay zero for every chunk
    #pragma unroll
    for (int k = 0; k < 10; ++k)
        *(f32x4*)(lds + tid * 16 + k * 8192) = f32x4{0.f, 0.f, 0.f, 0.f};

    // ---- compute ids ----
    const int lane = tid & 63;
    const int wv   = tid >> 6;              // 0..7
    const int ut   = wv & 1;
    const int yrh  = wv >> 1;               // 0..3 -> y rows 2*yrh, 2*yrh+1
    const int ln   = lane & 15;
    const int qd   = lane >> 4;

    const int offA0 = IN1_OFF + ((2 * yrh) * 16 + ln) * 64 + swz16(qd, ln);
    const int pB    = 16 * ut + ln;                          // in2 slot px (0..31)
    const int offB  = IN2_OFF + ((2 * yrh) * 32 + pB) * 64 + swz16(qd, pB);

    const float* in1b = in1 + (size_t)b * CHW_;
    const float* in2b = in2 + (size_t)b * CHW_;

    // ---- chunk-invariant staging assignments ----
    // in2: 512 units (16 rows x 8 px-quads x 4 ch-groups), 8 float4 each
    const int pp2 = tid & 7;
    const int g2  = (tid >> 3) & 3;
    const int r2i = tid >> 5;               // 0..15
    const int px2 = 4 * pp2;
    const int gx2 = xh * 16 - 8 + px2;      // aligned to 4 -> no straddle at W edges
    const int ry2 = yt * 8 - 4 + r2i;
    const bool valid2 = (gx2 >= 0) && (gx2 <= 124) && (ry2 >= 0) && (ry2 < H_);
    const int slot2 = r2i * 32 + px2;
    const float* sp2base = in2b + (size_t)(8 * g2) * HW_ + ry2 * W_ + gx2;

    // in1: 512 units (8 rows x 4 px-quads x 4 ch-groups x 4 ch-pairs), 2 float4 each
    const int pq1 = tid & 3;
    const int jj1 = (tid >> 2) & 3;
    const int g1  = (tid >> 4) & 3;
    const int r1i = tid >> 6;               // 0..7
    const int px1 = 4 * pq1;
    const int gx1 = xh * 16 + px1;
    const int y1  = yt * 8 + r1i;
    const int slot1 = r1i * 16 + px1;
    const float* sp1base = in1b + (size_t)(8 * g1 + 2 * jj1) * HW_ + y1 * W_ + gx1;

    f32x4 r2[8], r1v[2];

    auto issue = [&](int kc) {
        const size_t ch = (size_t)kc * 32 * HW_;
        if (valid2) {
            #pragma unroll
            for (int j = 0; j < 8; ++j)
                r2[j] = *(const f32x4*)(sp2base + ch + (size_t)j * HW_);
        }
        r1v[0] = *(const f32x4*)(sp1base + ch);
        r1v[1] = *(const f32x4*)(sp1base + ch + HW_);
    };

    auto store = [&](char* __restrict__ buf) {
        if (valid2) {
            #pragma unroll
            for (int p = 0; p < 4; ++p) {
                union { __hip_bfloat162 h2[4]; short8 s8; } u;
                #pragma unroll
                for (int jj = 0; jj < 4; ++jj)
                    u.h2[jj] = __float22bfloat162_rn(float2{r2[2 * jj][p], r2[2 * jj + 1][p]});
                *(short8*)(buf + IN2_OFF + (slot2 + p) * 64 + swz16(g2, slot2 + p)) = u.s8;
            }
        }
        #pragma unroll
        for (int p = 0; p < 4; ++p) {
            __hip_bfloat162 h = __float22bfloat162_rn(float2{r1v[0][p], r1v[1][p]});
            *(__hip_bfloat162*)(buf + IN1_OFF + (slot1 + p) * 64 + swz16(g1, slot1 + p) + 4 * jj1) = h;
        }
    };

    f32x4 acc0[9], acc1[9];
    #pragma unroll
    for (int s = 0; s < 9; ++s) { acc0[s] = f32x4{0.f,0.f,0.f,0.f}; acc1[s] = f32x4{0.f,0.f,0.f,0.f}; }

    __syncthreads();   // zero-fill visible (no loads in flight yet)

    issue(0);

    for (int kc = 0; kc < 8; ++kc) {
        char* buf = lds + (kc & 1) * BUFSZ;
        store(buf);                 // waits (vmcnt) only on chunk-kc regs
        if (kc < 7) issue(kc + 1);  // fire next chunk's loads; in flight across barrier
        asm volatile("s_waitcnt lgkmcnt(0)" ::: "memory");   // ds_writes retired
        __builtin_amdgcn_s_barrier();                        // raw: no vmcnt drain
        asm volatile("" ::: "memory");
        // ---------------- MFMA: 2 A-frags, rolling B-window ----------------
        short8 a0  = *(const short8*)(buf + offA0);
        short8 a1  = *(const short8*)(buf + offA0 + 16 * 64);
        short8 blo = *(const short8*)(buf + offB);
        #pragma unroll
        for (int s = 0; s < 9; ++s) {
            short8 bhi = *(const short8*)(buf + offB + (s + 1) * IN2_ROWB);
            acc0[s] = __builtin_amdgcn_mfma_f32_16x16x32_bf16(a0, blo, acc0[s], 0, 0, 0);
            acc1[s] = __builtin_amdgcn_mfma_f32_16x16x32_bf16(a1, bhi, acc1[s], 0, 0, 0);
            blo = bhi;
        }
        // no second barrier: next iter writes the OTHER buffer; the lgkmcnt(0)
        // before the next barrier also drains this iter's ds_reads.
    }

    // ---------------- epilogue: LDS-transposed coalesced band extraction ----
    // Phase per dy (s): scatter band values into ep[y (0..7)][dx (0..8)][x (0..15)]
    // (4608 B at lds base, reused), then wave wv stores row y=wv coalesced:
    // each store instr = 4 groups x 16 lanes x 4 B = 4 contiguous 64 B chunks.
    __syncthreads();   // all waves done with staging buffers

    const float scale = 1.0f / 256.0f;
    float* outb = out + (size_t)b * 81 * HW_ + (size_t)(yt * 8) * W_ + xh * 16;

    #pragma unroll
    for (int s = 0; s < 9; ++s) {
        // scatter: lane holds D[m=qd*4+r][n=ln]; dx = ln-m-8+16ut; y = 2*yrh+yr
        #pragma unroll
        for (int yr = 0; yr < 2; ++yr) {
            const f32x4 a = yr ? acc1[s] : acc0[s];
            const int y = 2 * yrh + yr;
            #pragma unroll
            for (int r = 0; r < 4; ++r) {
                const int m  = qd * 4 + r;
                const int dx = ln - m - 8 + 16 * ut;
                if (dx >= -4 && dx <= 4)
                    *(float*)(lds + ((y * 9 + dx + 4) * 16 + m) * 4) = a[r] * scale;
            }
        }
        asm volatile("s_waitcnt lgkmcnt(0)" ::: "memory");
        __builtin_amdgcn_s_barrier();
        asm volatile("" ::: "memory");
        // gather+store: wave wv owns y=wv; 9 dx values in 3 passes of 4 groups
        #pragma unroll
        for (int i = 0; i < 3; ++i) {
            const int pidx = i * 4 + qd;     // dx index 0..11, valid < 9
            if (pidx < 9) {
                const float v = *(const float*)(lds + ((wv * 9 + pidx) * 16 + ln) * 4);
                outb[((size_t)(s * 9 + pidx) * H_ + wv) * W_ + ln] = v;
            }
        }
        asm volatile("s_waitcnt lgkmcnt(0)" ::: "memory");   // reads done -> ep reusable
        __builtin_amdgcn_s_barrier();                        // stores stay in flight
        asm volatile("" ::: "memory");
    }
}

extern "C" void kernel_launch(void* const* d_in, const int* in_sizes, int n_in,
                              void* d_out, int out_size, void* d_ws, size_t ws_size,
                              hipStream_t stream) {
    const float* in1 = (const float*)d_in[0];
    const float* in2 = (const float*)d_in[1];
    float* out = (float*)d_out;

    // 8 b x 12 y-tiles x 8 x-eighths = 768 blocks of 512 threads
    corr_mfma5<<<768, 512, 0, stream>>>(in1, in2, out);
}

// Round 5
// 245.736 us; speedup vs baseline: 1.1037x; 1.0070x over previous
//
#include <hip/hip_runtime.h>
#include <hip/hip_bf16.h>

// FlowNetC correlation via bf16 MFMA band-GEMM.
// out[b, (dy+4)*9+(dx+4), y, x] = (1/256) * sum_c in1[b,c,y,x] * in2[b,c,y+dy,x+dx]
// B=8, C=256, H=96, W=128, MD=4.
//
// v6: TRUE 2-deep load pipeline. v4/v5's "pipeline" had depth ~0: per chunk,
// store(k) waited on chunk k's loads BEFORE issue(k+1) fired, so consecutive
// chunks' global loads never overlapped in the memory system; each chunk
// exposed ~1-2k cycles of load-issue+latency covered only by ~500 cycles of
// compute (all pipes <10% busy, occ 21%). Now: two register banks, chunks
// unrolled by 2 (bank A = even chunks -> LDS buf0, bank B = odd -> buf1);
// issueX(k+2) sits right after storeX(k), so each bank's loads get ~2 full
// phases of latency cover and the other bank's loads stay in flight across
// every wait. Compiler's dependency-counted vmcnt waits do the rest.
// Staging pattern, geometry, and the v5 coalesced epilogue are unchanged.
//
// Block = (b, 8-row y-tile, 16-px x-eighth), 512 threads (8 waves).
// LDS: 2 buffers x 40 KB (in1 8x16 slots, in2 16x32 slots, 64 B/slot).
// Wave = (ut, yrh): 2 u-tiles x 4 y-row-pairs.

#define B_ 8
#define C_ 256
#define H_ 96
#define W_ 128
#define HW_ 12288
#define CHW_ 3145728

#define BUFSZ 40960
#define IN1_OFF 0            // in1: 8*16 = 128 slots
#define IN2_OFF 8192         // in2: 16*32 = 512 slots
#define IN2_ROWB (32 * 64)   // bytes per in2 LDS row

typedef __attribute__((ext_vector_type(8))) short short8;
typedef __attribute__((ext_vector_type(4))) float f32x4;

// bank swizzle on the 16B channel-group within a 64B pixel slot
__device__ __forceinline__ int swz16(int g, int slot) {
    return (g ^ (slot & 3) ^ ((slot >> 2) & 3)) * 16;
}

__global__ __launch_bounds__(512, 2) void corr_mfma6(
    const float* __restrict__ in1,
    const float* __restrict__ in2,
    float* __restrict__ out)
{
    __shared__ __align__(16) char lds[2 * BUFSZ];

    const int tid = threadIdx.x;

    // XCD swizzle: blk%8 -> XCD; each XCD owns one batch image, y-major walk.
    const int blk  = blockIdx.x;
    const int b    = blk & 7;
    const int rest = blk >> 3;        // 0..95
    const int yt   = rest >> 3;       // 0..11 (8-row tiles)
    const int xh   = rest & 7;        // 0..7  (16-px eighths)

    // zero both buffers once: halo/OOB slots stay zero for every chunk
    #pragma unroll
    for (int k = 0; k < 10; ++k)
        *(f32x4*)(lds + tid * 16 + k * 8192) = f32x4{0.f, 0.f, 0.f, 0.f};

    // ---- compute ids ----
    const int lane = tid & 63;
    const int wv   = tid >> 6;              // 0..7
    const int ut   = wv & 1;
    const int yrh  = wv >> 1;               // 0..3 -> y rows 2*yrh, 2*yrh+1
    const int ln   = lane & 15;
    const int qd   = lane >> 4;

    const int offA0 = IN1_OFF + ((2 * yrh) * 16 + ln) * 64 + swz16(qd, ln);
    const int pB    = 16 * ut + ln;                          // in2 slot px (0..31)
    const int offB  = IN2_OFF + ((2 * yrh) * 32 + pB) * 64 + swz16(qd, pB);

    const float* in1b = in1 + (size_t)b * CHW_;
    const float* in2b = in2 + (size_t)b * CHW_;

    // ---- chunk-invariant staging assignments ----
    // in2: 512 units (16 rows x 8 px-quads x 4 ch-groups), 8 float4 each
    const int pp2 = tid & 7;
    const int g2  = (tid >> 3) & 3;
    const int r2i = tid >> 5;               // 0..15
    const int px2 = 4 * pp2;
    const int gx2 = xh * 16 - 8 + px2;      // aligned to 4 -> no straddle at W edges
    const int ry2 = yt * 8 - 4 + r2i;
    const bool valid2 = (gx2 >= 0) && (gx2 <= 124) && (ry2 >= 0) && (ry2 < H_);
    const int slot2 = r2i * 32 + px2;
    const float* sp2base = in2b + (size_t)(8 * g2) * HW_ + ry2 * W_ + gx2;

    // in1: 512 units (8 rows x 4 px-quads x 4 ch-groups x 4 ch-pairs), 2 float4 each
    const int pq1 = tid & 3;
    const int jj1 = (tid >> 2) & 3;
    const int g1  = (tid >> 4) & 3;
    const int r1i = tid >> 6;               // 0..7
    const int px1 = 4 * pq1;
    const int gx1 = xh * 16 + px1;
    const int y1  = yt * 8 + r1i;
    const int slot1 = r1i * 16 + px1;
    const float* sp1base = in1b + (size_t)(8 * g1 + 2 * jj1) * HW_ + y1 * W_ + gx1;

    // ---- two independent register banks (static names: no dynamic indexing) ----
    f32x4 rA2[8], rA1[2];
    f32x4 rB2[8], rB1[2];

    auto issueA = [&](int kc) {
        const size_t ch = (size_t)kc * 32 * HW_;
        if (valid2) {
            #pragma unroll
            for (int j = 0; j < 8; ++j)
                rA2[j] = *(const f32x4*)(sp2base + ch + (size_t)j * HW_);
        }
        rA1[0] = *(const f32x4*)(sp1base + ch);
        rA1[1] = *(const f32x4*)(sp1base + ch + HW_);
    };
    auto issueB = [&](int kc) {
        const size_t ch = (size_t)kc * 32 * HW_;
        if (valid2) {
            #pragma unroll
            for (int j = 0; j < 8; ++j)
                rB2[j] = *(const f32x4*)(sp2base + ch + (size_t)j * HW_);
        }
        rB1[0] = *(const f32x4*)(sp1base + ch);
        rB1[1] = *(const f32x4*)(sp1base + ch + HW_);
    };

    auto storeA = [&](char* __restrict__ buf) {
        if (valid2) {
            #pragma unroll
            for (int p = 0; p < 4; ++p) {
                union { __hip_bfloat162 h2[4]; short8 s8; } u;
                #pragma unroll
                for (int jj = 0; jj < 4; ++jj)
                    u.h2[jj] = __float22bfloat162_rn(float2{rA2[2 * jj][p], rA2[2 * jj + 1][p]});
                *(short8*)(buf + IN2_OFF + (slot2 + p) * 64 + swz16(g2, slot2 + p)) = u.s8;
            }
        }
        #pragma unroll
        for (int p = 0; p < 4; ++p) {
            __hip_bfloat162 h = __float22bfloat162_rn(float2{rA1[0][p], rA1[1][p]});
            *(__hip_bfloat162*)(buf + IN1_OFF + (slot1 + p) * 64 + swz16(g1, slot1 + p) + 4 * jj1) = h;
        }
    };
    auto storeB = [&](char* __restrict__ buf) {
        if (valid2) {
            #pragma unroll
            for (int p = 0; p < 4; ++p) {
                union { __hip_bfloat162 h2[4]; short8 s8; } u;
                #pragma unroll
                for (int jj = 0; jj < 4; ++jj)
                    u.h2[jj] = __float22bfloat162_rn(float2{rB2[2 * jj][p], rB2[2 * jj + 1][p]});
                *(short8*)(buf + IN2_OFF + (slot2 + p) * 64 + swz16(g2, slot2 + p)) = u.s8;
            }
        }
        #pragma unroll
        for (int p = 0; p < 4; ++p) {
            __hip_bfloat162 h = __float22bfloat162_rn(float2{rB1[0][p], rB1[1][p]});
            *(__hip_bfloat162*)(buf + IN1_OFF + (slot1 + p) * 64 + swz16(g1, slot1 + p) + 4 * jj1) = h;
        }
    };

    f32x4 acc0[9], acc1[9];
    #pragma unroll
    for (int s = 0; s < 9; ++s) { acc0[s] = f32x4{0.f,0.f,0.f,0.f}; acc1[s] = f32x4{0.f,0.f,0.f,0.f}; }

    auto compute = [&](const char* __restrict__ buf) {
        short8 a0  = *(const short8*)(buf + offA0);
        short8 a1  = *(const short8*)(buf + offA0 + 16 * 64);
        short8 blo = *(const short8*)(buf + offB);
        #pragma unroll
        for (int s = 0; s < 9; ++s) {
            short8 bhi = *(const short8*)(buf + offB + (s + 1) * IN2_ROWB);
            acc0[s] = __builtin_amdgcn_mfma_f32_16x16x32_bf16(a0, blo, acc0[s], 0, 0, 0);
            acc1[s] = __builtin_amdgcn_mfma_f32_16x16x32_bf16(a1, bhi, acc1[s], 0, 0, 0);
            blo = bhi;
        }
    };

    __syncthreads();   // zero-fill visible (no loads in flight yet)

    issueA(0);         // bank A: even chunks -> buf0
    issueB(1);         // bank B: odd chunks  -> buf1

    #pragma unroll
    for (int k2 = 0; k2 < 4; ++k2) {
        // ---- A phase: chunk 2*k2 ----
        storeA(lds);                       // waits (counted) on bank A only; B in flight
        if (2 * k2 + 2 < 8) issueA(2 * k2 + 2);
        asm volatile("s_waitcnt lgkmcnt(0)" ::: "memory");   // ds_writes retired
        __builtin_amdgcn_s_barrier();                        // raw: no vmcnt drain
        asm volatile("" ::: "memory");
        compute(lds);
        // ---- B phase: chunk 2*k2+1 ----
        storeB(lds + BUFSZ);               // waits on bank B only; A in flight
        if (2 * k2 + 3 < 8) issueB(2 * k2 + 3);
        asm volatile("s_waitcnt lgkmcnt(0)" ::: "memory");
        __builtin_amdgcn_s_barrier();
        asm volatile("" ::: "memory");
        compute(lds + BUFSZ);
    }

    // ---------------- epilogue: LDS-transposed coalesced band extraction ----
    // Phase per dy (s): scatter band values into ep[y (0..7)][dx (0..8)][x (0..15)]
    // (4608 B at lds base, reused), then wave wv stores row y=wv coalesced:
    // each store instr = 4 groups x 16 lanes x 4 B = 4 contiguous 64 B chunks.
    __syncthreads();   // all waves done with staging buffers

    const float scale = 1.0f / 256.0f;
    float* outb = out + (size_t)b * 81 * HW_ + (size_t)(yt * 8) * W_ + xh * 16;

    #pragma unroll
    for (int s = 0; s < 9; ++s) {
        // scatter: lane holds D[m=qd*4+r][n=ln]; dx = ln-m-8+16ut; y = 2*yrh+yr
        #pragma unroll
        for (int yr = 0; yr < 2; ++yr) {
            const f32x4 a = yr ? acc1[s] : acc0[s];
            const int y = 2 * yrh + yr;
            #pragma unroll
            for (int r = 0; r < 4; ++r) {
                const int m  = qd * 4 + r;
                const int dx = ln - m - 8 + 16 * ut;
                if (dx >= -4 && dx <= 4)
                    *(float*)(lds + ((y * 9 + dx + 4) * 16 + m) * 4) = a[r] * scale;
            }
        }
        asm volatile("s_waitcnt lgkmcnt(0)" ::: "memory");
        __builtin_amdgcn_s_barrier();
        asm volatile("" ::: "memory");
        // gather+store: wave wv owns y=wv; 9 dx values in 3 passes of 4 groups
        #pragma unroll
        for (int i = 0; i < 3; ++i) {
            const int pidx = i * 4 + qd;     // dx index 0..11, valid < 9
            if (pidx < 9) {
                const float v = *(const float*)(lds + ((wv * 9 + pidx) * 16 + ln) * 4);
                outb[((size_t)(s * 9 + pidx) * H_ + wv) * W_ + ln] = v;
            }
        }
        asm volatile("s_waitcnt lgkmcnt(0)" ::: "memory");   // reads done -> ep reusable
        __builtin_amdgcn_s_barrier();                        // stores stay in flight
        asm volatile("" ::: "memory");
    }
}

extern "C" void kernel_launch(void* const* d_in, const int* in_sizes, int n_in,
                              void* d_out, int out_size, void* d_ws, size_t ws_size,
                              hipStream_t stream) {
    const float* in1 = (const float*)d_in[0];
    const float* in2 = (const float*)d_in[1];
    float* out = (float*)d_out;

    // 8 b x 12 y-tiles x 8 x-eighths = 768 blocks of 512 threads
    corr_mfma6<<<768, 512, 0, stream>>>(in1, in2, out);
}